// Round 2
// baseline (585.978 us; speedup 1.0000x reference)
//
#include <hip/hip_runtime.h>
#include <hip/hip_bf16.h>
#include <math.h>

// Problem constants (from reference)
#define N_VARS    100000
#define D_DIM     512
#define C_CLUST   4096
#define K_VARS    32
#define E_EDGES   16384
#define S_SHARED  16
#define H_HEADS   4
#define CAP       32      // max contributions tracked per var (Poisson(2.62) -> P(>=32) ~ 1e-26)
#define NEG_SLOPE 0.2f

typedef __bf16 bf16x8_t __attribute__((ext_vector_type(8)));
typedef float  f32x4_t  __attribute__((ext_vector_type(4)));

__device__ __forceinline__ unsigned int f32_to_bf16_bits(float f) {
    unsigned int u = __builtin_bit_cast(unsigned int, f);
    unsigned int lsb = (u >> 16) & 1u;
    u += 0x7fffu + lsb;   // round-to-nearest-even
    return u >> 16;
}
__device__ __forceinline__ unsigned int pack_bf16x2(float a, float b) {
    return (f32_to_bf16_bits(b) << 16) | f32_to_bf16_bits(a);
}

// Robust decode of the active_heads scalar (int expected; tolerate float encoding).
__device__ __forceinline__ int decode_active_heads(const int* p) {
    int raw = p[0];
    if (raw >= 1 && raw <= H_HEADS) return raw;
    float f = __builtin_bit_cast(float, raw);
    if (f >= 1.0f && f <= (float)H_HEADS) return (int)f;
    return H_HEADS;
}

// ---------------------------------------------------------------------------
// 0) Convert the three 512x512 f32 weight matrices to bf16 (packed u32 pairs).
//    blockIdx.y selects the matrix. Each thread packs 2 elements.
__global__ void convert_w_kernel(const float* __restrict__ Wq,
                                 const float* __restrict__ Wk,
                                 const float* __restrict__ Wv,
                                 unsigned int* __restrict__ Wb) {
    const float* W = (blockIdx.y == 0) ? Wq : (blockIdx.y == 1) ? Wk : Wv;
    int i = blockIdx.x * blockDim.x + threadIdx.x;         // word index [0, 512*512/2)
    float2 w = ((const float2*)W)[i];
    Wb[(size_t)blockIdx.y * (D_DIM * D_DIM / 2) + i] = pack_bf16x2(w.x, w.y);
}

// ---------------------------------------------------------------------------
// 1) Per-cluster mean pool: cf_bf16[C, D] = bf16(mean_k x_var[cvid[c,k], :])
//    One block per cluster; thread t handles dims 2t, 2t+1 (coalesced float2).
__global__ void pool_kernel(const float* __restrict__ x,
                            const int* __restrict__ cvid,
                            unsigned int* __restrict__ cfb /* packed bf16x2 */) {
    int c = blockIdx.x;
    int t = threadIdx.x;  // 0..255
    float a0 = 0.f, a1 = 0.f;
#pragma unroll 4
    for (int k = 0; k < K_VARS; ++k) {
        int v = cvid[c * K_VARS + k];
        float2 w = ((const float2*)(x + (size_t)v * D_DIM))[t];
        a0 += w.x;
        a1 += w.y;
    }
    const float inv = 1.0f / (float)K_VARS;
    cfb[(size_t)c * (D_DIM / 2) + t] = pack_bf16x2(a0 * inv, a1 * inv);
}

// ---------------------------------------------------------------------------
// 2) QKV GEMM via MFMA 16x16x32 bf16. O[m,n] = sum_k cf[m,k] * W[n,k]
//    (both operands row-major, K contiguous -> direct 16B fragment loads).
//    Block = 4 waves; wave w computes tile (bx*64 + w*16, by*16). z selects Q/K/V.
__global__ __launch_bounds__(256) void gemm_kernel(
        const unsigned short* __restrict__ cfb,
        const unsigned short* __restrict__ Wb,
        float* __restrict__ Qo, float* __restrict__ Ko, float* __restrict__ Vo) {
    const unsigned short* W = Wb + (size_t)blockIdx.z * D_DIM * D_DIM;
    float* O = (blockIdx.z == 0) ? Qo : (blockIdx.z == 1) ? Ko : Vo;

    int wave = threadIdx.x >> 6;
    int lane = threadIdx.x & 63;
    int m0 = blockIdx.x * 64 + wave * 16;
    int n0 = blockIdx.y * 16;
    int mr = m0 + (lane & 15);
    int nr = n0 + (lane & 15);
    int kb = (lane >> 4) * 8;

    f32x4_t acc = {0.f, 0.f, 0.f, 0.f};
    for (int k0 = 0; k0 < D_DIM; k0 += 32) {
        bf16x8_t a = *(const bf16x8_t*)(cfb + (size_t)mr * D_DIM + k0 + kb);
        bf16x8_t b = *(const bf16x8_t*)(W   + (size_t)nr * D_DIM + k0 + kb);
        acc = __builtin_amdgcn_mfma_f32_16x16x32_bf16(a, b, acc, 0, 0, 0);
    }
    // C/D layout: col = lane&15 (n), row = (lane>>4)*4 + reg (m)  [m89-verified]
    int col = n0 + (lane & 15);
    int rb  = m0 + (lane >> 4) * 4;
#pragma unroll
    for (int r = 0; r < 4; ++r)
        O[(size_t)(rb + r) * D_DIM + col] = acc[r];
}

// ---------------------------------------------------------------------------
// 3) Edge attention: one wave per edge. attn[e] = hw_mean * sigmoid(leaky(QK/sqrt(D)))
__global__ void score_kernel(const float* __restrict__ Q,
                             const float* __restrict__ Kc,
                             const int* __restrict__ cei,
                             const float* __restrict__ hw,
                             const int* __restrict__ active_heads,
                             float* __restrict__ attn) {
    int e = blockIdx.x * 4 + (threadIdx.x >> 6);
    int lane = threadIdx.x & 63;
    int c1 = cei[e];
    int c2 = cei[E_EDGES + e];
    const float* q = Q  + (size_t)c1 * D_DIM;
    const float* k = Kc + (size_t)c2 * D_DIM;
    float s = 0.f;
#pragma unroll
    for (int j = 0; j < 8; ++j)
        s += q[lane + 64 * j] * k[lane + 64 * j];
#pragma unroll
    for (int off = 32; off > 0; off >>= 1)
        s += __shfl_xor(s, off);
    if (lane == 0) {
        int ah = decode_active_heads(active_heads);
        float m = 0.f;
        for (int h = 0; h < ah; ++h) m += hw[h];
        m /= (float)ah;
        float sc = s * (1.0f / sqrtf((float)D_DIM));
        sc = sc >= 0.f ? sc : NEG_SLOPE * sc;
        attn[e] = m / (1.f + __expf(-sc));
    }
}

// ---------------------------------------------------------------------------
// 4a) Build per-var contribution buckets (inverted scatter).
__global__ void fill_kernel(const int* __restrict__ shared_vars,
                            int* __restrict__ counts,
                            int* __restrict__ bucket) {
    int j = blockIdx.x * blockDim.x + threadIdx.x;
    if (j >= E_EDGES * S_SHARED) return;
    int v = shared_vars[j];
    int pos = atomicAdd(&counts[v], 1);
    if (pos < CAP) bucket[(size_t)v * CAP + pos] = j >> 4;  // edge id (S==16)
}

// 4b) One block per var: out[v,:] = x[v,:] + sum_e attn[e]*V[c2[e],:]   (all f32)
__global__ void gather_kernel(const float* __restrict__ x,
                              const float* __restrict__ V,
                              const float* __restrict__ attn,
                              const int* __restrict__ cei,
                              const int* __restrict__ counts,
                              const int* __restrict__ bucket,
                              float* __restrict__ out) {
    int v = blockIdx.x;
    int t = threadIdx.x;  // dims 2t, 2t+1
    float2 xx = ((const float2*)(x + (size_t)v * D_DIM))[t];
    float a0 = xx.x, a1 = xx.y;
    int cnt = counts[v];
    if (cnt > CAP) cnt = CAP;
    for (int k = 0; k < cnt; ++k) {
        int e  = bucket[(size_t)v * CAP + k];
        int c2 = cei[E_EDGES + e];
        float a = attn[e];
        float2 vv = ((const float2*)(V + (size_t)c2 * D_DIM))[t];
        a0 += a * vv.x;
        a1 += a * vv.y;
    }
    float2 o; o.x = a0; o.y = a1;
    ((float2*)(out + (size_t)v * D_DIM))[t] = o;
}

// ---------------------------------------------------------------------------
extern "C" void kernel_launch(void* const* d_in, const int* in_sizes, int n_in,
                              void* d_out, int out_size, void* d_ws, size_t ws_size,
                              hipStream_t stream) {
    const float* x_var = (const float*)d_in[0];
    const float* W_Q   = (const float*)d_in[1];
    const float* W_K   = (const float*)d_in[2];
    const float* W_V   = (const float*)d_in[3];
    const float* hw    = (const float*)d_in[4];
    const int* cvid  = (const int*)d_in[5];
    const int* cei   = (const int*)d_in[6];
    const int* shv   = (const int*)d_in[7];
    const int* ahp   = (const int*)d_in[8];

    char* ws = (char*)d_ws;
    const size_t MiB = 1024 * 1024;
    // workspace layout
    unsigned int* cfb = (unsigned int*)(ws + 0);          // bf16 [C,D] packed: 4 MiB
    unsigned int* Wb  = (unsigned int*)(ws + 4  * MiB);   // bf16 3x[D,D] packed: 1.5 MiB
    float* Q    = (float*)(ws + 6  * MiB);                // 8 MiB
    float* Kc   = (float*)(ws + 14 * MiB);                // 8 MiB
    float* V    = (float*)(ws + 22 * MiB);                // 8 MiB
    float* attn = (float*)(ws + 30 * MiB);                // 64 KiB
    int* counts = (int*)(ws + 30 * MiB + 65536);          // 400 KB
    int* bucket = (int*)(ws + 31 * MiB);                  // 12.8 MB -> ends ~43.3 MiB

    convert_w_kernel<<<dim3(D_DIM * D_DIM / 2 / 256, 3), 256, 0, stream>>>(
        W_Q, W_K, W_V, Wb);

    pool_kernel<<<C_CLUST, 256, 0, stream>>>(x_var, cvid, cfb);

    gemm_kernel<<<dim3(C_CLUST / 64, D_DIM / 16, 3), 256, 0, stream>>>(
        (const unsigned short*)cfb, (const unsigned short*)Wb, Q, Kc, V);

    score_kernel<<<E_EDGES / 4, 256, 0, stream>>>(Q, Kc, cei, hw, ahp, attn);

    hipMemsetAsync(counts, 0, (size_t)N_VARS * sizeof(int), stream);
    fill_kernel<<<(E_EDGES * S_SHARED + 255) / 256, 256, 0, stream>>>(shv, counts, bucket);

    gather_kernel<<<N_VARS, 256, 0, stream>>>(x_var, V, attn, cei, counts, bucket,
                                              (float*)d_out);
}

// Round 3
// 531.170 us; speedup vs baseline: 1.1032x; 1.1032x over previous
//
#include <hip/hip_runtime.h>
#include <hip/hip_bf16.h>
#include <math.h>

// Problem constants (from reference)
#define N_VARS    100000
#define D_DIM     512
#define C_CLUST   4096
#define K_VARS    32
#define E_EDGES   16384
#define S_SHARED  16
#define H_HEADS   4
#define CAP       32      // max contributions tracked per var (Poisson(2.62) -> P(>=32) ~ 1e-26)
#define NEG_SLOPE 0.2f

typedef __bf16 bf16x8_t __attribute__((ext_vector_type(8)));
typedef float  f32x4_t  __attribute__((ext_vector_type(4)));

__device__ __forceinline__ unsigned int f32_to_bf16_bits(float f) {
    unsigned int u = __builtin_bit_cast(unsigned int, f);
    unsigned int lsb = (u >> 16) & 1u;
    u += 0x7fffu + lsb;   // round-to-nearest-even
    return u >> 16;
}
__device__ __forceinline__ unsigned int pack_bf16x2(float a, float b) {
    return (f32_to_bf16_bits(b) << 16) | f32_to_bf16_bits(a);
}
__device__ __forceinline__ float bf16_bits_to_f32(unsigned int h) {
    unsigned int u = h << 16;
    return __builtin_bit_cast(float, u);
}

// Robust decode of the active_heads scalar (int expected; tolerate float encoding).
__device__ __forceinline__ int decode_active_heads(const int* p) {
    int raw = p[0];
    if (raw >= 1 && raw <= H_HEADS) return raw;
    float f = __builtin_bit_cast(float, raw);
    if (f >= 1.0f && f <= (float)H_HEADS) return (int)f;
    return H_HEADS;
}

// ---------------------------------------------------------------------------
// 0) Convert the three 512x512 f32 weight matrices to bf16 (packed u32 pairs).
__global__ void convert_w_kernel(const float* __restrict__ Wq,
                                 const float* __restrict__ Wk,
                                 const float* __restrict__ Wv,
                                 unsigned int* __restrict__ Wb) {
    const float* W = (blockIdx.y == 0) ? Wq : (blockIdx.y == 1) ? Wk : Wv;
    int i = blockIdx.x * blockDim.x + threadIdx.x;         // word index [0, 512*512/2)
    float2 w = ((const float2*)W)[i];
    Wb[(size_t)blockIdx.y * (D_DIM * D_DIM / 2) + i] = pack_bf16x2(w.x, w.y);
}

// ---------------------------------------------------------------------------
// 1) Per-cluster mean pool. 2 clusters per 256-block; 128 threads/cluster,
//    thread handles dims 4t..4t+3 via float4 (16 B/lane).
__global__ void pool_kernel(const float* __restrict__ x,
                            const int* __restrict__ cvid,
                            uint2* __restrict__ cfb /* packed bf16, 4/entry */) {
    int c = blockIdx.x * 2 + (threadIdx.x >> 7);
    int t = threadIdx.x & 127;  // float4 index within row
    float4 acc = {0.f, 0.f, 0.f, 0.f};
#pragma unroll 4
    for (int k = 0; k < K_VARS; ++k) {
        int v = cvid[c * K_VARS + k];
        float4 w = ((const float4*)(x + (size_t)v * D_DIM))[t];
        acc.x += w.x; acc.y += w.y; acc.z += w.z; acc.w += w.w;
    }
    const float inv = 1.0f / (float)K_VARS;
    uint2 o;
    o.x = pack_bf16x2(acc.x * inv, acc.y * inv);
    o.y = pack_bf16x2(acc.z * inv, acc.w * inv);
    cfb[(size_t)c * (D_DIM / 4) + t] = o;
}

// ---------------------------------------------------------------------------
// 2) QKV GEMM via MFMA 16x16x32 bf16. O[m,n] = sum_k cf[m,k] * W[n,k].
//    Block = 4 waves; block tile 64(m) x 64(n). Wave w: rows w*16..+16, all
//    64 cols as 4 independent acc chains (A fragment reused 4x). z = Q/K/V.
__global__ __launch_bounds__(256) void gemm_kernel(
        const unsigned short* __restrict__ cfb,
        const unsigned short* __restrict__ Wb,
        float* __restrict__ Qo, float* __restrict__ Ko, float* __restrict__ Vo) {
    const unsigned short* W = Wb + (size_t)blockIdx.z * D_DIM * D_DIM;
    float* O = (blockIdx.z == 0) ? Qo : (blockIdx.z == 1) ? Ko : Vo;

    int wave = threadIdx.x >> 6;
    int lane = threadIdx.x & 63;
    int m0 = blockIdx.x * 64 + wave * 16;
    int n0 = blockIdx.y * 64;
    int mr = m0 + (lane & 15);
    int kb = (lane >> 4) * 8;

    f32x4_t acc0 = {0.f,0.f,0.f,0.f}, acc1 = {0.f,0.f,0.f,0.f};
    f32x4_t acc2 = {0.f,0.f,0.f,0.f}, acc3 = {0.f,0.f,0.f,0.f};
    const unsigned short* arow = cfb + (size_t)mr * D_DIM + kb;
    const unsigned short* b0r  = W + (size_t)(n0 +  0 + (lane & 15)) * D_DIM + kb;
    const unsigned short* b1r  = W + (size_t)(n0 + 16 + (lane & 15)) * D_DIM + kb;
    const unsigned short* b2r  = W + (size_t)(n0 + 32 + (lane & 15)) * D_DIM + kb;
    const unsigned short* b3r  = W + (size_t)(n0 + 48 + (lane & 15)) * D_DIM + kb;
#pragma unroll 4
    for (int k0 = 0; k0 < D_DIM; k0 += 32) {
        bf16x8_t a  = *(const bf16x8_t*)(arow + k0);
        bf16x8_t b0 = *(const bf16x8_t*)(b0r + k0);
        bf16x8_t b1 = *(const bf16x8_t*)(b1r + k0);
        bf16x8_t b2 = *(const bf16x8_t*)(b2r + k0);
        bf16x8_t b3 = *(const bf16x8_t*)(b3r + k0);
        acc0 = __builtin_amdgcn_mfma_f32_16x16x32_bf16(a, b0, acc0, 0, 0, 0);
        acc1 = __builtin_amdgcn_mfma_f32_16x16x32_bf16(a, b1, acc1, 0, 0, 0);
        acc2 = __builtin_amdgcn_mfma_f32_16x16x32_bf16(a, b2, acc2, 0, 0, 0);
        acc3 = __builtin_amdgcn_mfma_f32_16x16x32_bf16(a, b3, acc3, 0, 0, 0);
    }
    // C/D layout: col = lane&15 (n), row = (lane>>4)*4 + reg (m)  [m89-verified]
    int rb = m0 + (lane >> 4) * 4;
    int cl = lane & 15;
#pragma unroll
    for (int r = 0; r < 4; ++r) {
        float* orow = O + (size_t)(rb + r) * D_DIM + n0 + cl;
        orow[ 0] = acc0[r];
        orow[16] = acc1[r];
        orow[32] = acc2[r];
        orow[48] = acc3[r];
    }
}

// ---------------------------------------------------------------------------
// 3) Edge attention: one wave per edge. attn[e] = hw_mean * sigmoid(leaky(QK/sqrt(D)))
__global__ void score_kernel(const float* __restrict__ Q,
                             const float* __restrict__ Kc,
                             const int* __restrict__ cei,
                             const float* __restrict__ hw,
                             const int* __restrict__ active_heads,
                             float* __restrict__ attn) {
    int e = blockIdx.x * 4 + (threadIdx.x >> 6);
    int lane = threadIdx.x & 63;
    int c1 = cei[e];
    int c2 = cei[E_EDGES + e];
    const float4* q = (const float4*)(Q  + (size_t)c1 * D_DIM);
    const float4* k = (const float4*)(Kc + (size_t)c2 * D_DIM);
    float4 qa = q[lane], qb = q[lane + 64];
    float4 ka = k[lane], kb = k[lane + 64];
    float s = qa.x*ka.x + qa.y*ka.y + qa.z*ka.z + qa.w*ka.w
            + qb.x*kb.x + qb.y*kb.y + qb.z*kb.z + qb.w*kb.w;
#pragma unroll
    for (int off = 32; off > 0; off >>= 1)
        s += __shfl_xor(s, off);
    if (lane == 0) {
        int ah = decode_active_heads(active_heads);
        float m = 0.f;
        for (int h = 0; h < ah; ++h) m += hw[h];
        m /= (float)ah;
        float sc = s * (1.0f / sqrtf((float)D_DIM));
        sc = sc >= 0.f ? sc : NEG_SLOPE * sc;
        attn[e] = m / (1.f + __expf(-sc));
    }
}

// ---------------------------------------------------------------------------
// 4a) Build per-var contribution buckets (inverted scatter). Runs AFTER score
//     so each bucket entry packs (attn_bf16 << 16) | c2  (C=4096 fits 12 bits)
//     -> gather's per-edge chain is bucket -> V row (2 loads, not 4).
__global__ void fill_kernel(const int* __restrict__ shared_vars,
                            const int* __restrict__ cei,
                            const float* __restrict__ attn,
                            int* __restrict__ counts,
                            unsigned int* __restrict__ bucket) {
    int j = blockIdx.x * blockDim.x + threadIdx.x;
    if (j >= E_EDGES * S_SHARED) return;
    int v = shared_vars[j];
    int e = j >> 4;  // S == 16
    int pos = atomicAdd(&counts[v], 1);
    if (pos < CAP) {
        unsigned int packed = (f32_to_bf16_bits(attn[e]) << 16) | (unsigned int)cei[E_EDGES + e];
        bucket[(size_t)v * CAP + pos] = packed;
    }
}

// 4b) 2 vars per 256-block: out[v,:] = x[v,:] + sum attn*V[c2,:]  (float4 lanes)
__global__ void gather_kernel(const float* __restrict__ x,
                              const float* __restrict__ V,
                              const int* __restrict__ counts,
                              const unsigned int* __restrict__ bucket,
                              float* __restrict__ out) {
    int v = blockIdx.x * 2 + (threadIdx.x >> 7);
    int t = threadIdx.x & 127;  // float4 index
    float4 a = ((const float4*)(x + (size_t)v * D_DIM))[t];
    int cnt = counts[v];
    if (cnt > CAP) cnt = CAP;
    const unsigned int* bk = bucket + (size_t)v * CAP;
    for (int k = 0; k < cnt; ++k) {
        unsigned int pw = bk[k];
        float at = bf16_bits_to_f32(pw >> 16);
        int c2 = pw & 0xFFFu;
        float4 vv = ((const float4*)(V + (size_t)c2 * D_DIM))[t];
        a.x += at * vv.x; a.y += at * vv.y; a.z += at * vv.z; a.w += at * vv.w;
    }
    ((float4*)(out + (size_t)v * D_DIM))[t] = a;
}

// ---------------------------------------------------------------------------
extern "C" void kernel_launch(void* const* d_in, const int* in_sizes, int n_in,
                              void* d_out, int out_size, void* d_ws, size_t ws_size,
                              hipStream_t stream) {
    const float* x_var = (const float*)d_in[0];
    const float* W_Q   = (const float*)d_in[1];
    const float* W_K   = (const float*)d_in[2];
    const float* W_V   = (const float*)d_in[3];
    const float* hw    = (const float*)d_in[4];
    const int* cvid  = (const int*)d_in[5];
    const int* cei   = (const int*)d_in[6];
    const int* shv   = (const int*)d_in[7];
    const int* ahp   = (const int*)d_in[8];

    char* ws = (char*)d_ws;
    const size_t MiB = 1024 * 1024;
    // workspace layout (~43.3 MiB total, same as known-good R2 footprint)
    unsigned int* cfb = (unsigned int*)(ws + 0);          // bf16 [C,D] packed: 4 MiB
    unsigned int* Wb  = (unsigned int*)(ws + 4  * MiB);   // bf16 3x[D,D] packed: 1.5 MiB
    float* Q    = (float*)(ws + 6  * MiB);                // 8 MiB
    float* Kc   = (float*)(ws + 14 * MiB);                // 8 MiB
    float* V    = (float*)(ws + 22 * MiB);                // 8 MiB
    float* attn = (float*)(ws + 30 * MiB);                // 64 KiB
    int* counts = (int*)(ws + 30 * MiB + 65536);          // 400 KB
    unsigned int* bucket = (unsigned int*)(ws + 31 * MiB);// 12.8 MB

    convert_w_kernel<<<dim3(D_DIM * D_DIM / 2 / 256, 3), 256, 0, stream>>>(
        W_Q, W_K, W_V, Wb);

    pool_kernel<<<C_CLUST / 2, 256, 0, stream>>>(x_var, cvid, (uint2*)cfb);

    gemm_kernel<<<dim3(C_CLUST / 64, D_DIM / 64, 3), 256, 0, stream>>>(
        (const unsigned short*)cfb, (const unsigned short*)Wb, Q, Kc, V);

    score_kernel<<<E_EDGES / 4, 256, 0, stream>>>(Q, Kc, cei, hw, ahp, attn);

    hipMemsetAsync(counts, 0, (size_t)N_VARS * sizeof(int), stream);
    fill_kernel<<<(E_EDGES * S_SHARED + 255) / 256, 256, 0, stream>>>(
        shv, cei, attn, counts, bucket);

    gather_kernel<<<N_VARS / 2, 256, 0, stream>>>(x_var, V, counts, bucket,
                                                  (float*)d_out);
}